// Round 4
// baseline (514.915 us; speedup 1.0000x reference)
//
#include <hip/hip_runtime.h>
#include <stdint.h>

#define NN 8192
#define FIN 128
#define FH 64
#define FO 16
#define BM 32                 // rows per block tile (was 64): 1024 blocks = 4/CU
#define BN 64
#define SPLIT 4
#define NRANGE (NN / SPLIT)   // 2048
#define NCHUNK (NRANGE / BN)  // 32

typedef float f32x4 __attribute__((ext_vector_type(4)));

static __device__ __forceinline__ void fma4(float4& acc, float a, const float4 s) {
  acc.x = fmaf(a, s.x, acc.x);
  acc.y = fmaf(a, s.y, acc.y);
  acc.z = fmaf(a, s.z, acc.z);
  acc.w = fmaf(a, s.w, acc.w);
}

// ---------------- S1 = x @ W1  (8192x128 @ 128x64) ----------------
__global__ __launch_bounds__(256) void k_s1(const float* __restrict__ x,
                                            const float* __restrict__ W1,
                                            float* __restrict__ S1) {
  __shared__ float W1l[FIN * FH];      // 32 KB
  __shared__ float xl[16][FIN + 4];
  const int t = threadIdx.x;
  const int n0 = blockIdx.x * 16;
  for (int i = t; i < FIN * FH / 4; i += 256)
    ((float4*)W1l)[i] = ((const float4*)W1)[i];
  for (int i = t; i < 16 * FIN; i += 256) {
    int r = i >> 7, c = i & (FIN - 1);
    xl[r][c] = x[(size_t)(n0 + r) * FIN + c];
  }
  __syncthreads();
  const int m = t >> 4;
  const int j0 = (t & 15) << 2;
  float4 acc = {0.f, 0.f, 0.f, 0.f};
#pragma unroll 8
  for (int k = 0; k < FIN; ++k) {
    float xv = xl[m][k];
    float4 w = *(const float4*)&W1l[k * FH + j0];
    fma4(acc, xv, w);
  }
  *(float4*)&S1[(size_t)(n0 + m) * FH + j0] = acc;
}

// ---------------- pass 1: hpart[sp] = (softmax(pi1)·adj) @ S1, register-prefetched ----------
__global__ __launch_bounds__(256) void k_pass1(const float* __restrict__ adj,
                                               const float* __restrict__ S1,
                                               const float* __restrict__ pi1,
                                               float* __restrict__ hpart) {
  __shared__ float Alds[BN][BM];   // [n][m ^ (n&28)]  8 KB
  __shared__ float S1l[BN][FH];    // 16 KB
  const int t = threadIdx.x;
  const int mb = blockIdx.x >> 2;  // 0..255 row-block
  const int sp = blockIdx.x & 3;

  float p0 = pi1[0], p1 = pi1[1], p2 = pi1[2], p3 = pi1[3];
  float mx = fmaxf(fmaxf(p0, p1), fmaxf(p2, p3));
  float e0 = expf(p0 - mx), e1 = expf(p1 - mx), e2 = expf(p2 - mx), e3 = expf(p3 - mx);
  float inv = 1.0f / (e0 + e1 + e2 + e3);
  const float w0 = e0 * inv, w1 = e1 * inv, w2 = e2 * inv, w3 = e3 * inv;

  const size_t NN2 = (size_t)NN * NN;
  const size_t row0 = (size_t)mb * BM;
  const int nbase = sp * NRANGE;

  const int n4 = t & 15;           // n-quad 0..15 (staging)
  const int ms = t >> 4;           // row slot 0..15 (staging), row = ms + 16*p, p<2
  const int mm = (t & 15) << 1;    // compute: 2-row base
  const int j0 = (t >> 4) << 2;    // compute: 4-col base

  f32x4 pf[2][4];                  // adj prefetch regs
  f32x4 pfS[4];                    // S1 prefetch

  float4 accA = {0,0,0,0}, accB = {0,0,0,0};

  auto ISSUE = [&](int c) {
    const int n0 = nbase + c * BN;
#pragma unroll
    for (int p = 0; p < 2; ++p) {
      const float* g = adj + (row0 + (size_t)(ms + (p << 4))) * NN + (size_t)(n0 + (n4 << 2));
      pf[p][0] = __builtin_nontemporal_load((const f32x4*)g);
      pf[p][1] = __builtin_nontemporal_load((const f32x4*)(g + NN2));
      pf[p][2] = __builtin_nontemporal_load((const f32x4*)(g + 2 * NN2));
      pf[p][3] = __builtin_nontemporal_load((const f32x4*)(g + 3 * NN2));
    }
    const f32x4* src = (const f32x4*)(S1 + (size_t)n0 * FH);
#pragma unroll
    for (int i = 0; i < 4; ++i) pfS[i] = src[t + 256 * i];
  };

  auto STAGE = [&]() {
#pragma unroll
    for (int p = 0; p < 2; ++p) {
      const int mc = (ms + (p << 4)) ^ ((n4 << 2) & 28);
      f32x4 a0 = pf[p][0], a1 = pf[p][1], a2 = pf[p][2], a3 = pf[p][3];
      Alds[(n4 << 2) + 0][mc] = fmaf(w0, a0.x, fmaf(w1, a1.x, fmaf(w2, a2.x, w3 * a3.x)));
      Alds[(n4 << 2) + 1][mc] = fmaf(w0, a0.y, fmaf(w1, a1.y, fmaf(w2, a2.y, w3 * a3.y)));
      Alds[(n4 << 2) + 2][mc] = fmaf(w0, a0.z, fmaf(w1, a1.z, fmaf(w2, a2.z, w3 * a3.z)));
      Alds[(n4 << 2) + 3][mc] = fmaf(w0, a0.w, fmaf(w1, a1.w, fmaf(w2, a2.w, w3 * a3.w)));
    }
    f32x4* dst = (f32x4*)&S1l[0][0];
#pragma unroll
    for (int i = 0; i < 4; ++i) dst[t + 256 * i] = pfS[i];
  };

  ISSUE(0);
  for (int c = 0; c < NCHUNK; ++c) {
    __syncthreads();                 // drains vmcnt(0): prefetched loads had a full compute phase
    STAGE();
    if (c + 1 < NCHUNK) ISSUE(c + 1);   // next chunk's loads fly during compute below
    asm volatile("s_waitcnt lgkmcnt(0)" ::: "memory");  // ds_writes visible; vmcnt NOT drained
    __builtin_amdgcn_s_barrier();
#pragma unroll 4
    for (int n = 0; n < BN; ++n) {
      const float2 a = *(const float2*)&Alds[n][mm ^ (n & 28)];
      const float4 s = *(const float4*)&S1l[n][j0];
      fma4(accA, a.x, s);
      fma4(accB, a.y, s);
    }
  }
  float* hp = hpart + (size_t)sp * NN * FH;
  const size_t rbase = (row0 + mm) * FH + j0;
  *(float4*)&hp[rbase]      = accA;
  *(float4*)&hp[rbase + FH] = accB;
}

// ---------------- exact JAX threefry2x32 dropout (partitionable path), key=(0,42) ----------
__device__ __forceinline__ float dropout_scale(uint32_t e) {
  uint32_t x0 = 0u;
  uint32_t x1 = e;
  const uint32_t ks1 = 42u;
  const uint32_t ks2 = 0x1BD11BF0u;
  x1 += ks1;
#define TFR(d) { x0 += x1; x1 = (x1 << d) | (x1 >> (32 - d)); x1 ^= x0; }
  TFR(13) TFR(15) TFR(26) TFR(6)   x0 += ks1; x1 += ks2 + 1u;
  TFR(17) TFR(29) TFR(16) TFR(24)  x0 += ks2; x1 += 0u  + 2u;
  TFR(13) TFR(15) TFR(26) TFR(6)   x0 += 0u;  x1 += ks1 + 3u;
  TFR(17) TFR(29) TFR(16) TFR(24)  x0 += ks1; x1 += ks2 + 4u;
  TFR(13) TFR(15) TFR(26) TFR(6)   x0 += ks2; x1 += 0u  + 5u;
#undef TFR
  uint32_t bits = x0 ^ x1;
  float u = __uint_as_float((bits >> 9) | 0x3f800000u) - 1.0f;
  return (u < 0.7f) ? (1.0f / 0.7f) : 0.0f;
}

// ---------------- mid: h = dropout(relu(sum_sp hpart + b1)); HW = h @ W2 ----------------
__global__ __launch_bounds__(256) void k_mid(const float* __restrict__ hpart,
                                             const float* __restrict__ b1,
                                             const float* __restrict__ W2,
                                             float* __restrict__ HW) {
  __shared__ float hl[4][FH];
  __shared__ float W2l[FH * FO];
  const int t = threadIdx.x;
  const int n0 = blockIdx.x << 2;
  for (int i = t; i < FH * FO; i += 256) W2l[i] = W2[i];
  const int j = t & 63, r = t >> 6;
  const uint32_t idx = (uint32_t)(n0 + r) * FH + j;
  const size_t NF = (size_t)NN * FH;
  float pre = hpart[idx] + hpart[idx + NF] + hpart[idx + 2 * NF] + hpart[idx + 3 * NF] + b1[j];
  float v = fmaxf(pre, 0.0f) * dropout_scale(idx);
  hl[r][j] = v;
  __syncthreads();
  if (t < 64) {
    const int rr = t >> 4, f = t & 15;
    float s = 0.f;
#pragma unroll 8
    for (int jj = 0; jj < FH; ++jj)
      s = fmaf(hl[rr][jj], W2l[jj * FO + f], s);
    HW[(size_t)(n0 + rr) * FO + f] = s;
  }
}

// ---------------- pass 2: opart[sp] = (pi2·adj) @ HW, register-prefetched ----------------
__global__ __launch_bounds__(256) void k_pass2(const float* __restrict__ adj,
                                               const float* __restrict__ HW,
                                               const float* __restrict__ pi2,
                                               float* __restrict__ opart) {
  __shared__ float Alds[BN][BM];   // 8 KB
  __shared__ float HWl[BN * FO];   // 4 KB
  const int t = threadIdx.x;
  const int mb = blockIdx.x >> 2;
  const int sp = blockIdx.x & 3;

  const float w0 = pi2[0], w1 = pi2[1], w2 = pi2[2], w3 = pi2[3];  // NOT softmaxed

  const size_t NN2 = (size_t)NN * NN;
  const size_t row0 = (size_t)mb * BM;
  const int nbase = sp * NRANGE;

  const int n4 = t & 15;
  const int ms = t >> 4;
  const int mm = (t & 15) << 1;
  const int f  = t >> 4;

  f32x4 pf[2][4];
  f32x4 pfH;

  float2 acc = {0, 0};

  auto ISSUE = [&](int c) {
    const int n0 = nbase + c * BN;
#pragma unroll
    for (int p = 0; p < 2; ++p) {
      const float* g = adj + (row0 + (size_t)(ms + (p << 4))) * NN + (size_t)(n0 + (n4 << 2));
      pf[p][0] = __builtin_nontemporal_load((const f32x4*)g);
      pf[p][1] = __builtin_nontemporal_load((const f32x4*)(g + NN2));
      pf[p][2] = __builtin_nontemporal_load((const f32x4*)(g + 2 * NN2));
      pf[p][3] = __builtin_nontemporal_load((const f32x4*)(g + 3 * NN2));
    }
    pfH = ((const f32x4*)(HW + (size_t)n0 * FO))[t];
  };

  auto STAGE = [&]() {
#pragma unroll
    for (int p = 0; p < 2; ++p) {
      const int mc = (ms + (p << 4)) ^ ((n4 << 2) & 28);
      f32x4 a0 = pf[p][0], a1 = pf[p][1], a2 = pf[p][2], a3 = pf[p][3];
      Alds[(n4 << 2) + 0][mc] = fmaf(w0, a0.x, fmaf(w1, a1.x, fmaf(w2, a2.x, w3 * a3.x)));
      Alds[(n4 << 2) + 1][mc] = fmaf(w0, a0.y, fmaf(w1, a1.y, fmaf(w2, a2.y, w3 * a3.y)));
      Alds[(n4 << 2) + 2][mc] = fmaf(w0, a0.z, fmaf(w1, a1.z, fmaf(w2, a2.z, w3 * a3.z)));
      Alds[(n4 << 2) + 3][mc] = fmaf(w0, a0.w, fmaf(w1, a1.w, fmaf(w2, a2.w, w3 * a3.w)));
    }
    ((f32x4*)HWl)[t] = pfH;
  };

  ISSUE(0);
  for (int c = 0; c < NCHUNK; ++c) {
    __syncthreads();
    STAGE();
    if (c + 1 < NCHUNK) ISSUE(c + 1);
    asm volatile("s_waitcnt lgkmcnt(0)" ::: "memory");
    __builtin_amdgcn_s_barrier();
#pragma unroll 4
    for (int n = 0; n < BN; ++n) {
      const float2 a = *(const float2*)&Alds[n][mm ^ (n & 28)];
      const float hv = HWl[n * FO + f];
      acc.x = fmaf(a.x, hv, acc.x);
      acc.y = fmaf(a.y, hv, acc.y);
    }
  }
  float* op = opart + (size_t)sp * NN * FO;
  const size_t r = (row0 + mm) * FO + f;
  op[r]      = acc.x;
  op[r + FO] = acc.y;
}

// ---------------- final: out = sum_sp opart + b2 ----------------
__global__ __launch_bounds__(256) void k_fin(const float* __restrict__ opart,
                                             const float* __restrict__ b2,
                                             float* __restrict__ out) {
  const int e = blockIdx.x * 256 + threadIdx.x;
  const size_t NFo = (size_t)NN * FO;
  out[e] = opart[e] + opart[e + NFo] + opart[e + 2 * NFo] + opart[e + 3 * NFo] + b2[e & 15];
}

extern "C" void kernel_launch(void* const* d_in, const int* in_sizes, int n_in,
                              void* d_out, int out_size, void* d_ws, size_t ws_size,
                              hipStream_t stream) {
  const float* adj = (const float*)d_in[0];
  const float* x   = (const float*)d_in[1];
  const float* W1  = (const float*)d_in[2];
  const float* b1  = (const float*)d_in[3];
  const float* W2  = (const float*)d_in[4];
  const float* b2  = (const float*)d_in[5];
  const float* pi1 = (const float*)d_in[6];
  const float* pi2 = (const float*)d_in[7];
  float* out = (float*)d_out;
  float* ws  = (float*)d_ws;

  // ws layout (floats): S1[8192*64] | hpart[4*8192*64] | HW[8192*16] | opart[4*8192*16]
  float* S1    = ws;
  float* hpart = S1 + (size_t)NN * FH;
  float* HW    = hpart + (size_t)SPLIT * NN * FH;
  float* opart = HW + (size_t)NN * FO;

  k_s1   <<<NN / 16,           256, 0, stream>>>(x, W1, S1);
  k_pass1<<<(NN / BM) * SPLIT, 256, 0, stream>>>(adj, S1, pi1, hpart);
  k_mid  <<<NN / 4,            256, 0, stream>>>(hpart, b1, W2, HW);
  k_pass2<<<(NN / BM) * SPLIT, 256, 0, stream>>>(adj, HW, pi2, opart);
  k_fin  <<<(NN * FO) / 256,   256, 0, stream>>>(opart, b2, out);
}

// Round 5
// 346.496 us; speedup vs baseline: 1.4861x; 1.4861x over previous
//
#include <hip/hip_runtime.h>
#include <stdint.h>

#define NN 8192
#define FIN 128
#define FH 64
#define FO 16
#define BM 64
#define BN 64
#define SPLIT 4
#define NRANGE (NN / SPLIT)   // 2048
#define NCHUNK (NRANGE / BN)  // 32

typedef float   f32x4 __attribute__((ext_vector_type(4)));
typedef _Float16 f16x4 __attribute__((ext_vector_type(4)));

static __device__ __forceinline__ void fma4(float4& acc, float a, const float4 s) {
  acc.x = fmaf(a, s.x, acc.x);
  acc.y = fmaf(a, s.y, acc.y);
  acc.z = fmaf(a, s.z, acc.z);
  acc.w = fmaf(a, s.w, acc.w);
}

// ---------------- S1 = x @ W1  (8192x128 @ 128x64) ----------------
__global__ __launch_bounds__(256) void k_s1(const float* __restrict__ x,
                                            const float* __restrict__ W1,
                                            float* __restrict__ S1) {
  __shared__ float W1l[FIN * FH];
  __shared__ float xl[16][FIN + 4];
  const int t = threadIdx.x;
  const int n0 = blockIdx.x * 16;
  for (int i = t; i < FIN * FH / 4; i += 256)
    ((float4*)W1l)[i] = ((const float4*)W1)[i];
  for (int i = t; i < 16 * FIN; i += 256) {
    int r = i >> 7, c = i & (FIN - 1);
    xl[r][c] = x[(size_t)(n0 + r) * FIN + c];
  }
  __syncthreads();
  const int m = t >> 4;
  const int j0 = (t & 15) << 2;
  float4 acc = {0.f, 0.f, 0.f, 0.f};
#pragma unroll 8
  for (int k = 0; k < FIN; ++k) {
    float xv = xl[m][k];
    float4 w = *(const float4*)&W1l[k * FH + j0];
    fma4(acc, xv, w);
  }
  *(float4*)&S1[(size_t)(n0 + m) * FH + j0] = acc;
}

// ===== pass 1 (FUSED): hpart[sp] = (softmax(pi1)·adj)@S1 ; also emit A2h = fp16(pi2·adj) =====
__global__ __launch_bounds__(256) void k_pass1_fused(const float* __restrict__ adj,
                                                     const float* __restrict__ S1,
                                                     const float* __restrict__ pi1,
                                                     const float* __restrict__ pi2,
                                                     float* __restrict__ hpart,
                                                     _Float16* __restrict__ A2h) {
  __shared__ float Alds[BN][BM];   // [n][m ^ (n&60)]  16 KB
  __shared__ float S1l[BN][FH];    // 16 KB
  const int t = threadIdx.x;
  const int mb = blockIdx.x >> 2;
  const int sp = blockIdx.x & 3;

  float p0 = pi1[0], p1 = pi1[1], p2 = pi1[2], p3 = pi1[3];
  float mx = fmaxf(fmaxf(p0, p1), fmaxf(p2, p3));
  float e0 = expf(p0 - mx), e1 = expf(p1 - mx), e2 = expf(p2 - mx), e3 = expf(p3 - mx);
  float inv = 1.0f / (e0 + e1 + e2 + e3);
  const float w0 = e0 * inv, w1 = e1 * inv, w2 = e2 * inv, w3 = e3 * inv;
  const float v0 = pi2[0], v1 = pi2[1], v2 = pi2[2], v3 = pi2[3];   // raw pi2

  const size_t NN2 = (size_t)NN * NN;
  const size_t row0 = (size_t)mb * BM;
  const int nbase = sp * NRANGE;

  const int n4 = t & 15;           // n-quad (staging)
  const int ms = t >> 4;           // row slot (staging), row = ms + 16*p
  const int m0 = (t & 15) << 2;    // compute 4x4 tile
  const int j0 = (t >> 4) << 2;

  f32x4 pf[4][4];
  f32x4 pfS[4];

  float4 acc0 = {0,0,0,0}, acc1 = {0,0,0,0}, acc2 = {0,0,0,0}, acc3 = {0,0,0,0};

  auto ISSUE = [&](int c) {
    const int n0 = nbase + c * BN;
#pragma unroll
    for (int p = 0; p < 4; ++p) {
      const float* g = adj + (row0 + (size_t)(ms + (p << 4))) * NN + (size_t)(n0 + (n4 << 2));
      pf[p][0] = __builtin_nontemporal_load((const f32x4*)g);
      pf[p][1] = __builtin_nontemporal_load((const f32x4*)(g + NN2));
      pf[p][2] = __builtin_nontemporal_load((const f32x4*)(g + 2 * NN2));
      pf[p][3] = __builtin_nontemporal_load((const f32x4*)(g + 3 * NN2));
    }
    const f32x4* src = (const f32x4*)(S1 + (size_t)n0 * FH);
#pragma unroll
    for (int i = 0; i < 4; ++i) pfS[i] = src[t + 256 * i];
  };

  auto STAGE = [&](int c) {
    const int n0 = nbase + c * BN;
#pragma unroll
    for (int p = 0; p < 4; ++p) {
      const int ml = ms + (p << 4);
      const int mc = ml ^ (n4 << 2);
      f32x4 a0 = pf[p][0], a1 = pf[p][1], a2 = pf[p][2], a3 = pf[p][3];
      // pi1 (softmaxed) combo -> LDS for this pass's GEMM
      Alds[(n4 << 2) + 0][mc] = fmaf(w0, a0.x, fmaf(w1, a1.x, fmaf(w2, a2.x, w3 * a3.x)));
      Alds[(n4 << 2) + 1][mc] = fmaf(w0, a0.y, fmaf(w1, a1.y, fmaf(w2, a2.y, w3 * a3.y)));
      Alds[(n4 << 2) + 2][mc] = fmaf(w0, a0.z, fmaf(w1, a1.z, fmaf(w2, a2.z, w3 * a3.z)));
      Alds[(n4 << 2) + 3][mc] = fmaf(w0, a0.w, fmaf(w1, a1.w, fmaf(w2, a2.w, w3 * a3.w)));
      // pi2 (raw) combo -> fp16 A2 tile for pass 2 (reuses the same adj registers)
      f16x4 h4;
      h4.x = (_Float16)fmaf(v0, a0.x, fmaf(v1, a1.x, fmaf(v2, a2.x, v3 * a3.x)));
      h4.y = (_Float16)fmaf(v0, a0.y, fmaf(v1, a1.y, fmaf(v2, a2.y, v3 * a3.y)));
      h4.z = (_Float16)fmaf(v0, a0.z, fmaf(v1, a1.z, fmaf(v2, a2.z, v3 * a3.z)));
      h4.w = (_Float16)fmaf(v0, a0.w, fmaf(v1, a1.w, fmaf(v2, a2.w, v3 * a3.w)));
      *(f16x4*)(A2h + (row0 + (size_t)ml) * NN + (size_t)(n0 + (n4 << 2))) = h4;
    }
    f32x4* dst = (f32x4*)&S1l[0][0];
#pragma unroll
    for (int i = 0; i < 4; ++i) dst[t + 256 * i] = pfS[i];
  };

  ISSUE(0);
  for (int c = 0; c < NCHUNK; ++c) {
    __syncthreads();                 // drains vmcnt(0): prefetched loads completed during compute
    STAGE(c);
    if (c + 1 < NCHUNK) ISSUE(c + 1);
    asm volatile("s_waitcnt lgkmcnt(0)" ::: "memory");
    __builtin_amdgcn_s_barrier();
#pragma unroll 4
    for (int n = 0; n < BN; ++n) {
      const float4 a = *(const float4*)&Alds[n][m0 ^ (n & 60)];
      const float4 s = *(const float4*)&S1l[n][j0];
      fma4(acc0, a.x, s);
      fma4(acc1, a.y, s);
      fma4(acc2, a.z, s);
      fma4(acc3, a.w, s);
    }
  }
  float* hp = hpart + (size_t)sp * NN * FH;
  const size_t rbase = (row0 + m0) * FH + j0;
  *(float4*)&hp[rbase]          = acc0;
  *(float4*)&hp[rbase + FH]     = acc1;
  *(float4*)&hp[rbase + 2 * FH] = acc2;
  *(float4*)&hp[rbase + 3 * FH] = acc3;
}

// ===== pass 1 (FALLBACK, no A2 emit — used when ws is too small) =====
__global__ __launch_bounds__(256) void k_pass1(const float* __restrict__ adj,
                                               const float* __restrict__ S1,
                                               const float* __restrict__ pi1,
                                               float* __restrict__ hpart) {
  __shared__ float Alds[BN][BM];
  __shared__ float S1l[BN][FH];
  const int t = threadIdx.x;
  const int mb = blockIdx.x >> 2;
  const int sp = blockIdx.x & 3;

  float p0 = pi1[0], p1 = pi1[1], p2 = pi1[2], p3 = pi1[3];
  float mx = fmaxf(fmaxf(p0, p1), fmaxf(p2, p3));
  float e0 = expf(p0 - mx), e1 = expf(p1 - mx), e2 = expf(p2 - mx), e3 = expf(p3 - mx);
  float inv = 1.0f / (e0 + e1 + e2 + e3);
  const float w0 = e0 * inv, w1 = e1 * inv, w2 = e2 * inv, w3 = e3 * inv;

  const size_t NN2 = (size_t)NN * NN;
  const size_t row0 = (size_t)mb * BM;
  const int nbase = sp * NRANGE;

  const int n4 = t & 15;
  const int ms = t >> 4;
  const int m0 = (t & 15) << 2;
  const int j0 = (t >> 4) << 2;

  f32x4 pf[4][4];
  f32x4 pfS[4];

  float4 acc0 = {0,0,0,0}, acc1 = {0,0,0,0}, acc2 = {0,0,0,0}, acc3 = {0,0,0,0};

  auto ISSUE = [&](int c) {
    const int n0 = nbase + c * BN;
#pragma unroll
    for (int p = 0; p < 4; ++p) {
      const float* g = adj + (row0 + (size_t)(ms + (p << 4))) * NN + (size_t)(n0 + (n4 << 2));
      pf[p][0] = __builtin_nontemporal_load((const f32x4*)g);
      pf[p][1] = __builtin_nontemporal_load((const f32x4*)(g + NN2));
      pf[p][2] = __builtin_nontemporal_load((const f32x4*)(g + 2 * NN2));
      pf[p][3] = __builtin_nontemporal_load((const f32x4*)(g + 3 * NN2));
    }
    const f32x4* src = (const f32x4*)(S1 + (size_t)n0 * FH);
#pragma unroll
    for (int i = 0; i < 4; ++i) pfS[i] = src[t + 256 * i];
  };

  auto STAGE = [&]() {
#pragma unroll
    for (int p = 0; p < 4; ++p) {
      const int mc = (ms + (p << 4)) ^ (n4 << 2);
      f32x4 a0 = pf[p][0], a1 = pf[p][1], a2 = pf[p][2], a3 = pf[p][3];
      Alds[(n4 << 2) + 0][mc] = fmaf(w0, a0.x, fmaf(w1, a1.x, fmaf(w2, a2.x, w3 * a3.x)));
      Alds[(n4 << 2) + 1][mc] = fmaf(w0, a0.y, fmaf(w1, a1.y, fmaf(w2, a2.y, w3 * a3.y)));
      Alds[(n4 << 2) + 2][mc] = fmaf(w0, a0.z, fmaf(w1, a1.z, fmaf(w2, a2.z, w3 * a3.z)));
      Alds[(n4 << 2) + 3][mc] = fmaf(w0, a0.w, fmaf(w1, a1.w, fmaf(w2, a2.w, w3 * a3.w)));
    }
    f32x4* dst = (f32x4*)&S1l[0][0];
#pragma unroll
    for (int i = 0; i < 4; ++i) dst[t + 256 * i] = pfS[i];
  };

  ISSUE(0);
  for (int c = 0; c < NCHUNK; ++c) {
    __syncthreads();
    STAGE();
    if (c + 1 < NCHUNK) ISSUE(c + 1);
    asm volatile("s_waitcnt lgkmcnt(0)" ::: "memory");
    __builtin_amdgcn_s_barrier();
#pragma unroll 4
    for (int n = 0; n < BN; ++n) {
      const float4 a = *(const float4*)&Alds[n][m0 ^ (n & 60)];
      const float4 s = *(const float4*)&S1l[n][j0];
      fma4(acc0, a.x, s);
      fma4(acc1, a.y, s);
      fma4(acc2, a.z, s);
      fma4(acc3, a.w, s);
    }
  }
  float* hp = hpart + (size_t)sp * NN * FH;
  const size_t rbase = (row0 + m0) * FH + j0;
  *(float4*)&hp[rbase]          = acc0;
  *(float4*)&hp[rbase + FH]     = acc1;
  *(float4*)&hp[rbase + 2 * FH] = acc2;
  *(float4*)&hp[rbase + 3 * FH] = acc3;
}

// ---------------- exact JAX threefry2x32 dropout (partitionable path), key=(0,42) ----------
__device__ __forceinline__ float dropout_scale(uint32_t e) {
  uint32_t x0 = 0u;
  uint32_t x1 = e;
  const uint32_t ks1 = 42u;
  const uint32_t ks2 = 0x1BD11BF0u;
  x1 += ks1;
#define TFR(d) { x0 += x1; x1 = (x1 << d) | (x1 >> (32 - d)); x1 ^= x0; }
  TFR(13) TFR(15) TFR(26) TFR(6)   x0 += ks1; x1 += ks2 + 1u;
  TFR(17) TFR(29) TFR(16) TFR(24)  x0 += ks2; x1 += 0u  + 2u;
  TFR(13) TFR(15) TFR(26) TFR(6)   x0 += 0u;  x1 += ks1 + 3u;
  TFR(17) TFR(29) TFR(16) TFR(24)  x0 += ks1; x1 += ks2 + 4u;
  TFR(13) TFR(15) TFR(26) TFR(6)   x0 += ks2; x1 += 0u  + 5u;
#undef TFR
  uint32_t bits = x0 ^ x1;
  float u = __uint_as_float((bits >> 9) | 0x3f800000u) - 1.0f;
  return (u < 0.7f) ? (1.0f / 0.7f) : 0.0f;
}

// ---------------- mid: h = dropout(relu(sum_sp hpart + b1)); HW = h @ W2 ----------------
__global__ __launch_bounds__(256) void k_mid(const float* __restrict__ hpart,
                                             const float* __restrict__ b1,
                                             const float* __restrict__ W2,
                                             float* __restrict__ HW) {
  __shared__ float hl[4][FH];
  __shared__ float W2l[FH * FO];
  const int t = threadIdx.x;
  const int n0 = blockIdx.x << 2;
  for (int i = t; i < FH * FO; i += 256) W2l[i] = W2[i];
  const int j = t & 63, r = t >> 6;
  const uint32_t idx = (uint32_t)(n0 + r) * FH + j;
  const size_t NF = (size_t)NN * FH;
  float pre = hpart[idx] + hpart[idx + NF] + hpart[idx + 2 * NF] + hpart[idx + 3 * NF] + b1[j];
  float v = fmaxf(pre, 0.0f) * dropout_scale(idx);
  hl[r][j] = v;
  __syncthreads();
  if (t < 64) {
    const int rr = t >> 4, f = t & 15;
    float s = 0.f;
#pragma unroll 8
    for (int jj = 0; jj < FH; ++jj)
      s = fmaf(hl[rr][jj], W2l[jj * FO + f], s);
    HW[(size_t)(n0 + rr) * FO + f] = s;
  }
}

// ===== pass 2 (FUSED): opart[sp] = A2h(fp16) @ HW — reads 128 MB instead of 1.07 GB =====
__global__ __launch_bounds__(256) void k_pass2_half(const _Float16* __restrict__ A2h,
                                                    const float* __restrict__ HW,
                                                    float* __restrict__ opart) {
  __shared__ float Alds[BN][BM];   // 16 KB
  __shared__ float HWl[BN * FO];   // 4 KB
  const int t = threadIdx.x;
  const int mb = blockIdx.x >> 2;
  const int sp = blockIdx.x & 3;

  const size_t row0 = (size_t)mb * BM;
  const int nbase = sp * NRANGE;

  const int n4 = t & 15;
  const int ms = t >> 4;
  const int m0 = (t & 15) << 2;
  const int f  = t >> 4;

  f16x4 pf[4];
  f32x4 pfH;

  float4 acc = {0,0,0,0};

  auto ISSUE = [&](int c) {
    const int n0 = nbase + c * BN;
#pragma unroll
    for (int p = 0; p < 4; ++p)
      pf[p] = *(const f16x4*)(A2h + (row0 + (size_t)(ms + (p << 4))) * NN + (size_t)(n0 + (n4 << 2)));
    pfH = ((const f32x4*)(HW + (size_t)n0 * FO))[t];
  };

  auto STAGE = [&]() {
#pragma unroll
    for (int p = 0; p < 4; ++p) {
      const int mc = (ms + (p << 4)) ^ (n4 << 2);
      Alds[(n4 << 2) + 0][mc] = (float)pf[p].x;
      Alds[(n4 << 2) + 1][mc] = (float)pf[p].y;
      Alds[(n4 << 2) + 2][mc] = (float)pf[p].z;
      Alds[(n4 << 2) + 3][mc] = (float)pf[p].w;
    }
    ((f32x4*)HWl)[t] = pfH;
  };

  ISSUE(0);
  for (int c = 0; c < NCHUNK; ++c) {
    __syncthreads();
    STAGE();
    if (c + 1 < NCHUNK) ISSUE(c + 1);
    asm volatile("s_waitcnt lgkmcnt(0)" ::: "memory");
    __builtin_amdgcn_s_barrier();
#pragma unroll 4
    for (int n = 0; n < BN; ++n) {
      const float4 a = *(const float4*)&Alds[n][m0 ^ (n & 60)];
      const float hv = HWl[n * FO + f];
      acc.x = fmaf(a.x, hv, acc.x);
      acc.y = fmaf(a.y, hv, acc.y);
      acc.z = fmaf(a.z, hv, acc.z);
      acc.w = fmaf(a.w, hv, acc.w);
    }
  }
  float* op = opart + (size_t)sp * NN * FO;
  const size_t r = (row0 + m0) * FO + f;
  op[r]          = acc.x;
  op[r + FO]     = acc.y;
  op[r + 2 * FO] = acc.z;
  op[r + 3 * FO] = acc.w;
}

// ===== pass 2 (FALLBACK): opart[sp] = (pi2·adj) @ HW =====
__global__ __launch_bounds__(256) void k_pass2(const float* __restrict__ adj,
                                               const float* __restrict__ HW,
                                               const float* __restrict__ pi2,
                                               float* __restrict__ opart) {
  __shared__ float Alds[BN][BM];
  __shared__ float HWl[BN * FO];
  const int t = threadIdx.x;
  const int mb = blockIdx.x >> 2;
  const int sp = blockIdx.x & 3;

  const float w0 = pi2[0], w1 = pi2[1], w2 = pi2[2], w3 = pi2[3];

  const size_t NN2 = (size_t)NN * NN;
  const size_t row0 = (size_t)mb * BM;
  const int nbase = sp * NRANGE;

  const int n4 = t & 15;
  const int ms = t >> 4;
  const int m0 = (t & 15) << 2;
  const int f  = t >> 4;

  f32x4 pf[4][4];
  f32x4 pfH;

  float4 acc = {0,0,0,0};

  auto ISSUE = [&](int c) {
    const int n0 = nbase + c * BN;
#pragma unroll
    for (int p = 0; p < 4; ++p) {
      const float* g = adj + (row0 + (size_t)(ms + (p << 4))) * NN + (size_t)(n0 + (n4 << 2));
      pf[p][0] = __builtin_nontemporal_load((const f32x4*)g);
      pf[p][1] = __builtin_nontemporal_load((const f32x4*)(g + NN2));
      pf[p][2] = __builtin_nontemporal_load((const f32x4*)(g + 2 * NN2));
      pf[p][3] = __builtin_nontemporal_load((const f32x4*)(g + 3 * NN2));
    }
    pfH = ((const f32x4*)(HW + (size_t)n0 * FO))[t];
  };

  auto STAGE = [&]() {
#pragma unroll
    for (int p = 0; p < 4; ++p) {
      const int mc = (ms + (p << 4)) ^ (n4 << 2);
      f32x4 a0 = pf[p][0], a1 = pf[p][1], a2 = pf[p][2], a3 = pf[p][3];
      Alds[(n4 << 2) + 0][mc] = fmaf(w0, a0.x, fmaf(w1, a1.x, fmaf(w2, a2.x, w3 * a3.x)));
      Alds[(n4 << 2) + 1][mc] = fmaf(w0, a0.y, fmaf(w1, a1.y, fmaf(w2, a2.y, w3 * a3.y)));
      Alds[(n4 << 2) + 2][mc] = fmaf(w0, a0.z, fmaf(w1, a1.z, fmaf(w2, a2.z, w3 * a3.z)));
      Alds[(n4 << 2) + 3][mc] = fmaf(w0, a0.w, fmaf(w1, a1.w, fmaf(w2, a2.w, w3 * a3.w)));
    }
    ((f32x4*)HWl)[t] = pfH;
  };

  ISSUE(0);
  for (int c = 0; c < NCHUNK; ++c) {
    __syncthreads();
    STAGE();
    if (c + 1 < NCHUNK) ISSUE(c + 1);
    asm volatile("s_waitcnt lgkmcnt(0)" ::: "memory");
    __builtin_amdgcn_s_barrier();
#pragma unroll 4
    for (int n = 0; n < BN; ++n) {
      const float4 a = *(const float4*)&Alds[n][m0 ^ (n & 60)];
      const float hv = HWl[n * FO + f];
      acc.x = fmaf(a.x, hv, acc.x);
      acc.y = fmaf(a.y, hv, acc.y);
      acc.z = fmaf(a.z, hv, acc.z);
      acc.w = fmaf(a.w, hv, acc.w);
    }
  }
  float* op = opart + (size_t)sp * NN * FO;
  const size_t r = (row0 + m0) * FO + f;
  op[r]          = acc.x;
  op[r + FO]     = acc.y;
  op[r + 2 * FO] = acc.z;
  op[r + 3 * FO] = acc.w;
}

// ---------------- final: out = sum_sp opart + b2 ----------------
__global__ __launch_bounds__(256) void k_fin(const float* __restrict__ opart,
                                             const float* __restrict__ b2,
                                             float* __restrict__ out) {
  const int e = blockIdx.x * 256 + threadIdx.x;
  const size_t NFo = (size_t)NN * FO;
  out[e] = opart[e] + opart[e + NFo] + opart[e + 2 * NFo] + opart[e + 3 * NFo] + b2[e & 15];
}

extern "C" void kernel_launch(void* const* d_in, const int* in_sizes, int n_in,
                              void* d_out, int out_size, void* d_ws, size_t ws_size,
                              hipStream_t stream) {
  const float* adj = (const float*)d_in[0];
  const float* x   = (const float*)d_in[1];
  const float* W1  = (const float*)d_in[2];
  const float* b1  = (const float*)d_in[3];
  const float* W2  = (const float*)d_in[4];
  const float* b2  = (const float*)d_in[5];
  const float* pi1 = (const float*)d_in[6];
  const float* pi2 = (const float*)d_in[7];
  float* out = (float*)d_out;
  float* ws  = (float*)d_ws;

  // ws layout (floats): S1[8192*64] | hpart[4*8192*64] | HW[8192*16] | opart[4*8192*16] | A2h(fp16)
  float* S1    = ws;
  float* hpart = S1 + (size_t)NN * FH;
  float* HW    = hpart + (size_t)SPLIT * NN * FH;
  float* opart = HW + (size_t)NN * FO;
  _Float16* A2h = (_Float16*)(opart + (size_t)SPLIT * NN * FO);

  const size_t base_bytes = (size_t)3276800 * 4;                 // 12.5 MiB
  const size_t need_bytes = base_bytes + (size_t)NN * NN * 2;    // + 128 MiB A2h

  k_s1<<<NN / 16, 256, 0, stream>>>(x, W1, S1);
  if (ws_size >= need_bytes) {
    k_pass1_fused<<<(NN / BM) * SPLIT, 256, 0, stream>>>(adj, S1, pi1, pi2, hpart, A2h);
    k_mid        <<<NN / 4,            256, 0, stream>>>(hpart, b1, W2, HW);
    k_pass2_half <<<(NN / BM) * SPLIT, 256, 0, stream>>>(A2h, HW, opart);
  } else {
    k_pass1<<<(NN / BM) * SPLIT, 256, 0, stream>>>(adj, S1, pi1, hpart);
    k_mid  <<<NN / 4,            256, 0, stream>>>(hpart, b1, W2, HW);
    k_pass2<<<(NN / BM) * SPLIT, 256, 0, stream>>>(adj, HW, pi2, opart);
  }
  k_fin<<<(NN * FO) / 256, 256, 0, stream>>>(opart, b2, out);
}